// Round 5
// baseline (1456.127 us; speedup 1.0000x reference)
//
#include <hip/hip_runtime.h>

typedef __bf16 bf16;
typedef __bf16 bf16x8 __attribute__((ext_vector_type(8)));
typedef float f32x4 __attribute__((ext_vector_type(4)));

#define N_DSTN 8192
#define TT 16
#define HROW 72            // shorts per h row (64 + 8 pad); 144B row keeps 16B align for b128
#define HBUF (32 * HROW)   // one parity buffer, in shorts

// ---- workspace layout (bytes) ----
#define WS_WHH  0          // bf16 [2][256][64]  pre-scaled
#define WS_WIH  65536      // bf16 [2][256][16]  pre-scaled
#define WS_BIAS 81920      // f32  [2][256]      (bih+bhh)*gs
#define WS_EW   83968      // bf16 [64][128]
#define WS_NW   100352     // bf16 [64][128]
#define WS_EB   116736     // f32  [64]
#define WS_NB   116992     // f32  [64]
#define WS_ATTN 117248     // f32  [64]
#define WS_T2W  117504     // f32  [8]
#define WS_T2B  117536     // f32  [8]
#define WS_HE   131072     // bf16 [8192*32][64]  final h_e (original edge order)  33.55 MB
#define WS_SC   33685504   // f32  [8192*32]      leaky-relu attention scores       1.05 MB

__device__ __forceinline__ f32x4 MFMA(bf16x8 a, bf16x8 b, f32x4 c) {
    return __builtin_amdgcn_mfma_f32_16x16x32_bf16(a, b, c, 0, 0, 0);
}
__device__ __forceinline__ float ldf(const void* p, long i, bool isb) {
    return isb ? (float)((const bf16*)p)[i] : ((const float*)p)[i];
}
// 8 consecutive elements as bf16x8; i must be a multiple of 4
__device__ __forceinline__ bf16x8 ld8v(const void* p, long i, bool isb) {
    if (isb) {
        return *reinterpret_cast<const bf16x8*>((const bf16*)p + i);
    } else {
        const float* f = (const float*)p + i;
        float4 u = *reinterpret_cast<const float4*>(f);
        float4 v = *reinterpret_cast<const float4*>(f + 4);
        bf16x8 r;
        r[0] = (bf16)u.x; r[1] = (bf16)u.y; r[2] = (bf16)u.z; r[3] = (bf16)u.w;
        r[4] = (bf16)v.x; r[5] = (bf16)v.y; r[6] = (bf16)v.z; r[7] = (bf16)v.w;
        return r;
    }
}

// ---------------- prep: convert/scale all params into workspace ----------------
extern "C" __global__ void gtea_prep(const void* __restrict__ e_times,
                                     const void* __restrict__ t2v_w,
                                     const void* __restrict__ t2v_b,
                                     const void* __restrict__ t2v_w0,
                                     const void* __restrict__ t2v_b0,
                                     const void* __restrict__ Wih_e,
                                     const void* __restrict__ Whh_e,
                                     const void* __restrict__ bih_e,
                                     const void* __restrict__ bhh_e,
                                     const void* __restrict__ Wih_a,
                                     const void* __restrict__ Whh_a,
                                     const void* __restrict__ bih_a,
                                     const void* __restrict__ bhh_a,
                                     const void* __restrict__ attn_w,
                                     const void* __restrict__ edge_out_W,
                                     const void* __restrict__ edge_out_b,
                                     const void* __restrict__ node_W,
                                     const void* __restrict__ node_b,
                                     void* __restrict__ ws)
{
    __shared__ int isb_s;
    const int tid = threadIdx.x;
    if (tid < 64) {
        const unsigned short* u = (const unsigned short*)e_times;
        unsigned short a = u[tid * 2], b = u[tid * 2 + 1];
        bool ok = (a <= 0x3F80u) && (b <= 0x3F80u);
        unsigned long long m = __ballot(ok);
        if (tid == 0) isb_s = (m == ~0ULL) ? 1 : 0;
    }
    __syncthreads();
    const bool isb = (isb_s != 0);
    char* wsb = (char*)ws;
    const int gstep = blockDim.x * gridDim.x;
    const int g0 = blockIdx.x * blockDim.x + tid;

    // Whh scaled: [2][256][64]
    for (int i = g0; i < 2 * 256 * 64; i += gstep) {
        int Lw = i >> 14, rem = i & 16383, n = rem >> 6;
        const void* W = Lw ? Whh_a : Whh_e;
        float gs = ((n >> 6) == 2) ? 2.88539008f : -1.44269504f;
        ((bf16*)(wsb + WS_WHH))[i] = (bf16)(ldf(W, rem, isb) * gs);
    }
    // Wih scaled: [2][256][16]
    for (int i = g0; i < 2 * 256 * 16; i += gstep) {
        int Lw = i >> 12, rem = i & 4095, n = rem >> 4;
        const void* W = Lw ? Wih_a : Wih_e;
        float gs = ((n >> 6) == 2) ? 2.88539008f : -1.44269504f;
        ((bf16*)(wsb + WS_WIH))[i] = (bf16)(ldf(W, rem, isb) * gs);
    }
    // bias scaled: [2][256]
    for (int i = g0; i < 2 * 256; i += gstep) {
        int Lw = i >> 8, n = i & 255;
        const void* bi = Lw ? bih_a : bih_e;
        const void* bh = Lw ? bhh_a : bhh_e;
        float gs = ((n >> 6) == 2) ? 2.88539008f : -1.44269504f;
        ((float*)(wsb + WS_BIAS))[i] = (ldf(bi, n, isb) + ldf(bh, n, isb)) * gs;
    }
    // edge_out_W / node_W → bf16
    for (int i = g0; i < 64 * 128; i += gstep) {
        ((bf16*)(wsb + WS_EW))[i] = (bf16)ldf(edge_out_W, i, isb);
        ((bf16*)(wsb + WS_NW))[i] = (bf16)ldf(node_W, i, isb);
    }
    for (int i = g0; i < 64; i += gstep) {
        ((float*)(wsb + WS_EB))[i]   = ldf(edge_out_b, i, isb);
        ((float*)(wsb + WS_NB))[i]   = ldf(node_b, i, isb);
        ((float*)(wsb + WS_ATTN))[i] = ldf(attn_w, i, isb);
    }
    if (g0 < 7) {
        ((float*)(wsb + WS_T2W))[g0] = ldf(t2v_w, g0, isb);
        ((float*)(wsb + WS_T2B))[g0] = ldf(t2v_b, g0, isb);
    }
    if (g0 == 7) {
        ((float*)(wsb + WS_T2W))[7] = ldf(t2v_w0, 0, isb);
        ((float*)(wsb + WS_T2B))[7] = ldf(t2v_b0, 0, isb);
    }
}

// ---------------- K1: LSTM kernel — one (edge-group, L) per 256-thread block ----------------
extern "C" __global__ void __launch_bounds__(256, 5)
gtea_lstm(const void* __restrict__ edge_feats,
          const void* __restrict__ e_times,
          const int*  __restrict__ e_len,
          void* __restrict__ ws)
{
    // LDS ≈ 19.9 KB
    __shared__ __align__(16) bf16 habuf[2][HBUF];       // 9216 B (parity double-buffer)
    __shared__ __align__(16) bf16 xslab[2][32 * 16];    // 2048 B (rolling x: feat|tenc)
    __shared__ __align__(16) bf16 wihb[256 * 16 + 16];  // 8224 B (this L's Wih + zero row)
    __shared__ int lens_sh[32], idx_sh[32];
    __shared__ int isb_sh;

    const int tid = threadIdx.x;
    const int w4  = tid >> 6;        // wave 0..3
    const int l   = tid & 63;
    const int l15 = l & 15;
    const int q   = l >> 4;
    const int u16 = w4 * 16 + l15;

    const int g  = blockIdx.x >> 1;
    const int L  = blockIdx.x & 1;   // 0: lstm_e, 1: lstm_a
    const int e0 = g * 32;
    char* wsb = (char*)ws;

    // ---- phase A: dtype sniff + in-wave length sort ----
    if (tid < 64) {
        const unsigned short* u = (const unsigned short*)e_times;
        unsigned short a = u[tid * 2], b = u[tid * 2 + 1];
        bool ok = (a <= 0x3F80u) && (b <= 0x3F80u);
        unsigned long long m = __ballot(ok);
        if (tid == 0) isb_sh = (m == ~0ULL) ? 1 : 0;
    }
    if (tid < 32) {
        int lj = e_len[e0 + tid];
        int rank = 0;
        for (int i = 0; i < 32; i++) {
            int li = __shfl(lj, i);
            rank += (li > lj) || (li == lj && i < tid);
        }
        int mt = rank >> 4, kp = rank & 15;
        int slot = mt * 16 + (kp & 3) * 4 + (kp >> 2);
        idx_sh[slot]  = tid;
        lens_sh[slot] = lj;
    }
    __syncthreads();
    const bool isb = (isb_sh != 0);

    // ---- phase B: stage Wih, derive masks, load Bh/bias, prefetch x(t=0) ----
    {
        const bf16x8* src = reinterpret_cast<const bf16x8*>(wsb + WS_WIH) + L * 512;
        bf16x8* dst = reinterpret_cast<bf16x8*>(wihb);
        dst[tid]       = src[tid];
        dst[tid + 256] = src[tid + 256];
        if (tid < 16) wihb[256 * 16 + tid] = (bf16)0.0f;
    }
    int gm0[4], gm1[4];
    #pragma unroll
    for (int r = 0; r < 4; r++) {
        gm0[r] = __builtin_amdgcn_readfirstlane(lens_sh[r]);
        gm1[r] = __builtin_amdgcn_readfirstlane(lens_sh[16 + r]);
    }
    const int tmax = gm0[0], mtmax1 = gm1[0];

    unsigned lp = 0;
    #pragma unroll
    for (int mt = 0; mt < 2; mt++)
        #pragma unroll
        for (int r = 0; r < 4; r++)
            lp |= (unsigned)(lens_sh[mt * 16 + q * 4 + r] - 1) << ((mt * 4 + r) * 4);

    const bf16*  wWhh  = (const bf16*)(wsb + WS_WHH) + (long)L * 256 * 64;
    const float* wBias = (const float*)(wsb + WS_BIAS) + L * 256;
    bf16x8 Bh[4][2];
    float  bias[4];
    #pragma unroll
    for (int j = 0; j < 4; j++) {
        int n = 64 * j + u16;
        Bh[j][0] = *reinterpret_cast<const bf16x8*>(wWhh + (long)n * 64 + q * 8);
        Bh[j][1] = *reinterpret_cast<const bf16x8*>(wWhh + (long)n * 64 + 32 + q * 8);
        bias[j] = wBias[n];
    }

    // rolling-x prefetch: 8 lanes per wave, 1 edge each
    auto prefetch_x = [&](int t, int par) {
        int s = w4 * 8 + (l & 7);
        int j = idx_sh[s];
        long base = (long)(e0 + j) * TT + t;
        bf16x8 f8 = ld8v(edge_feats, base * 8, isb);
        float tau = ldf(e_times, base, isb);
        const float* tw = (const float*)(wsb + WS_T2W);
        const float* tb = (const float*)(wsb + WS_T2B);
        bf16x8 te;
        #pragma unroll
        for (int i = 0; i < 7; i++) te[i] = (bf16)__sinf(tau * tw[i] + tb[i]);
        te[7] = (bf16)(tau * tw[7] + tb[7]);
        *reinterpret_cast<bf16x8*>(&xslab[par][s * 16])     = f8;
        *reinterpret_cast<bf16x8*>(&xslab[par][s * 16 + 8]) = te;
    };
    if (l < 8) prefetch_x(0, 0);

    const bf16* zrow   = &wihb[256 * 16];
    const bf16* bxp    = (q < 2) ? &wihb[u16 * 16 + q * 8] : zrow;
    const int   bx_str = (q < 2) ? (64 * 16) : 0;
    const bf16* xbase  = (q < 2) ? &xslab[0][l15 * 16 + q * 8] : zrow;
    const int   xa_m   = (q < 2) ? (16 * 16) : 0;   // mt stride (shorts)
    const int   xa_p   = (q < 2) ? (32 * 16) : 0;   // parity stride (shorts)

    const int rd_off = l15 * HROW + q * 8;
    const int wr_off = (q * 4) * HROW + u16;

    float c[2][4];
    #pragma unroll
    for (int mt = 0; mt < 2; mt++)
        #pragma unroll
        for (int r = 0; r < 4; r++) c[mt][r] = 0.0f;

    __syncthreads();

    // shared activation (gates pre-scaled: gi,gf,go = -x/ln2 ; gg = +2x/ln2)
    auto activ = [&](f32x4 (&D)[4], int mt, int r, bf16* hw) {
        float gi = D[0][r], gf = D[1][r];
        float gg = D[2][r], go = D[3][r];
        float ei = __builtin_amdgcn_exp2f(gi);
        float ef = __builtin_amdgcn_exp2f(gf);
        float eg = __builtin_amdgcn_exp2f(gg);
        float di = 1.0f + ei, dfv = 1.0f + ef, dg = 1.0f + eg;
        float m1 = di * dg;
        float R1 = __builtin_amdgcn_rcpf(m1 * dfv);
        float cn = (m1 * R1) * c[mt][r] + (eg - 1.0f) * (dfv * R1);
        c[mt][r] = cn;
        float eo = __builtin_amdgcn_exp2f(go);
        float ec = __builtin_amdgcn_exp2f(2.88539008f * cn);
        float R2 = __builtin_amdgcn_rcpf((1.0f + eo) * (1.0f + ec));
        float hn = (ec - 1.0f) * R2;
        hw[r * HROW] = (bf16)hn;
    };

    // ---- peeled t=0: h == 0, so no h-MFMAs, unmasked (all lens >= 1) ----
    {
        bf16* wp = &habuf[1][0] + wr_off;
        #pragma unroll
        for (int mt = 0; mt < 2; mt++) {
            bf16x8 xa = *reinterpret_cast<const bf16x8*>(xbase + mt * xa_m);
            f32x4 D[4];
            #pragma unroll
            for (int j = 0; j < 4; j++) {
                f32x4 acc = {bias[j], bias[j], bias[j], bias[j]};
                bf16x8 bx = *reinterpret_cast<const bf16x8*>(bxp + j * bx_str);
                acc = MFMA(xa, bx, acc);
                D[j] = acc;
            }
            bf16* hw = wp + mt * (16 * HROW);
            #pragma unroll
            for (int r = 0; r < 4; r++) activ(D, mt, r, hw);
        }
        if (l < 8 && 1 < tmax) prefetch_x(1, 1);
        __syncthreads();
    }

    // ---- main recurrent loop ----
    auto do_mt = [&](int mt, int t, const bf16* rp, bf16* wp, const bf16* xpt) {
        const bf16* hr = rp + mt * (16 * HROW);
        bf16x8 ah0 = *reinterpret_cast<const bf16x8*>(hr);
        bf16x8 ah1 = *reinterpret_cast<const bf16x8*>(hr + 32);
        bf16x8 xa  = *reinterpret_cast<const bf16x8*>(xpt + mt * xa_m);
        f32x4 D[4];
        #pragma unroll
        for (int j = 0; j < 4; j++) {
            f32x4 acc = {bias[j], bias[j], bias[j], bias[j]};
            acc = MFMA(ah0, Bh[j][0], acc);
            acc = MFMA(ah1, Bh[j][1], acc);
            bf16x8 bx = *reinterpret_cast<const bf16x8*>(bxp + j * bx_str);
            acc = MFMA(xa, bx, acc);
            D[j] = acc;
        }
        bf16* hw = wp + mt * (16 * HROW);
        #pragma unroll
        for (int r = 0; r < 4; r++) {
            int gmax = mt ? gm1[r] : gm0[r];
            if (t < gmax) {
                int lm1 = (int)((lp >> ((mt * 4 + r) * 4)) & 15u);
                if (t <= lm1) activ(D, mt, r, hw);
            }
        }
    };

    for (int t = 1; t < tmax; t++) {
        const bf16* rp = &habuf[t & 1][0] + rd_off;
        bf16*       wp = &habuf[(t + 1) & 1][0] + wr_off;
        const bf16* xpt = xbase + (t & 1) * xa_p;
        do_mt(0, t, rp, wp, xpt);
        if (t < mtmax1) do_mt(1, t, rp, wp, xpt);
        if (l < 8 && t + 1 < tmax) prefetch_x(t + 1, (t + 1) & 1);
        __syncthreads();
    }

    // ---- finalize: write h_last (L=0) or attention scores (L=1), original edge order ----
    {
        int s = tid >> 3, c8 = tid & 7;
        const bf16* ha = &habuf[lens_sh[s] & 1][s * HROW + c8 * 8];
        bf16x8 hv = *reinterpret_cast<const bf16x8*>(ha);
        if (L == 0) {
            *reinterpret_cast<bf16x8*>((bf16*)(wsb + WS_HE) +
                ((long)(e0 + idx_sh[s])) * 64 + c8 * 8) = hv;
        } else {
            const float* af = (const float*)(wsb + WS_ATTN);
            float p = 0.0f;
            #pragma unroll
            for (int i = 0; i < 8; i++) p += (float)hv[i] * af[c8 * 8 + i];
            p += __shfl_xor(p, 1);
            p += __shfl_xor(p, 2);
            p += __shfl_xor(p, 4);
            if (c8 == 0)
                ((float*)(wsb + WS_SC))[e0 + idx_sh[s]] = (p > 0.0f) ? p : 0.01f * p;
        }
    }
}

// ---------------- K2: epilogue — sparsemax + m-GEMM + h_neigh + output ----------------
extern "C" __global__ void __launch_bounds__(256, 4)
gtea_epi(const void* __restrict__ node_features,
         const int*  __restrict__ edge_src,
         const void* __restrict__ e_times,
         const void* __restrict__ ws,
         void* __restrict__ outp)
{
    __shared__ float vbuf[128];
    __shared__ float alpha_sh[32];
    __shared__ int isb_sh;

    const int tid = threadIdx.x;
    const int w4  = tid >> 6;
    const int l   = tid & 63;
    const int l15 = l & 15;
    const int q   = l >> 4;
    const int u16 = w4 * 16 + l15;

    const int d  = blockIdx.x;
    const int e0 = d * 32;
    const char* wsb = (const char*)ws;

    if (tid < 64) {
        const unsigned short* u = (const unsigned short*)e_times;
        unsigned short a = u[tid * 2], b = u[tid * 2 + 1];
        bool ok = (a <= 0x3F80u) && (b <= 0x3F80u);
        unsigned long long m = __ballot(ok);
        if (tid == 0) isb_sh = (m == ~0ULL) ? 1 : 0;
    }
    __syncthreads();
    const bool isb = (isb_sh != 0);

    if (tid < 64) vbuf[tid] = ldf(node_features, (long)d * 64 + tid, isb);

    // m = relu([h_src | h_e] @ edge_out_W^T + b)   (original edge order)
    float mval[2][4];
    {
        const bf16* wEW = (const bf16*)(wsb + WS_EW);
        bf16x8 Bw[4];
        #pragma unroll
        for (int ks = 0; ks < 4; ks++)
            Bw[ks] = *reinterpret_cast<const bf16x8*>(wEW + (long)u16 * 128 + ks * 32 + q * 8);
        float mb = ((const float*)(wsb + WS_EB))[u16];
        const bf16* hE = (const bf16*)(wsb + WS_HE);
        #pragma unroll
        for (int mt = 0; mt < 2; mt++) {
            int e_loc = mt * 16 + l15;
            int src = edge_src[e0 + e_loc];
            bf16x8 a0 = ld8v(node_features, (long)src * 64 + q * 8, isb);
            bf16x8 a1 = ld8v(node_features, (long)src * 64 + 32 + q * 8, isb);
            bf16x8 a2 = *reinterpret_cast<const bf16x8*>(hE + (long)(e0 + e_loc) * 64 + q * 8);
            bf16x8 a3 = *reinterpret_cast<const bf16x8*>(hE + (long)(e0 + e_loc) * 64 + 32 + q * 8);
            f32x4 acc = {mb, mb, mb, mb};
            acc = MFMA(a0, Bw[0], acc);
            acc = MFMA(a1, Bw[1], acc);
            acc = MFMA(a2, Bw[2], acc);
            acc = MFMA(a3, Bw[3], acc);
            #pragma unroll
            for (int r = 0; r < 4; r++) mval[mt][r] = fmaxf(acc[r], 0.0f);
        }
    }

    if (tid < 64) {   // sparsemax (reference-exact)
        float z = (tid < 32) ? ((const float*)(wsb + WS_SC))[e0 + tid] : -3.0e38f;
        float zm = z;
        #pragma unroll
        for (int m = 32; m >= 1; m >>= 1) zm = fmaxf(zm, __shfl_xor(zm, m));
        z -= zm;
        int cnt = 0; float sb = 0.0f;
        for (int i = 0; i < 32; i++) {
            float zi = __shfl(z, i);
            bool before = (zi > z) || (zi == z && i < tid);
            if (before) { cnt++; sb += zi; }
        }
        float r = (float)(cnt + 1);
        float S = sb + z;
        bool isgt = (tid < 32) && (1.0f + r * z > S);
        float kf  = isgt ? r : 0.0f;
        float sgt = isgt ? z : 0.0f;
        #pragma unroll
        for (int m = 32; m >= 1; m >>= 1) kf = fmaxf(kf, __shfl_xor(kf, m));
        #pragma unroll
        for (int m = 32; m >= 1; m >>= 1) sgt += __shfl_xor(sgt, m);
        float tau = (sgt - 1.0f) / fmaxf(kf, 1.0f);
        if (tid < 32) alpha_sh[tid] = fmaxf(z - tau, 0.0f);
    }
    __syncthreads();

    {   // h_neigh
        float hn = 0.0f;
        #pragma unroll
        for (int mt = 0; mt < 2; mt++)
            #pragma unroll
            for (int r = 0; r < 4; r++)
                hn += alpha_sh[mt * 16 + q * 4 + r] * mval[mt][r];
        hn += __shfl_xor(hn, 16);
        hn += __shfl_xor(hn, 32);
        if (q == 0) vbuf[64 + u16] = hn;
    }
    __syncthreads();

    {   // final matvec, in-wave 4-way reduction
        int u = tid >> 2, kq = tid & 3;
        const bf16* wNW = (const bf16*)(wsb + WS_NW);
        bf16x8 wv0 = *reinterpret_cast<const bf16x8*>(wNW + (long)u * 128 + kq * 32);
        bf16x8 wv1 = *reinterpret_cast<const bf16x8*>(wNW + (long)u * 128 + kq * 32 + 8);
        bf16x8 wv2 = *reinterpret_cast<const bf16x8*>(wNW + (long)u * 128 + kq * 32 + 16);
        bf16x8 wv3 = *reinterpret_cast<const bf16x8*>(wNW + (long)u * 128 + kq * 32 + 24);
        float acc = 0.0f;
        #pragma unroll
        for (int i = 0; i < 8; i++) {
            acc += (float)wv0[i] * vbuf[kq * 32 + i];
            acc += (float)wv1[i] * vbuf[kq * 32 + 8 + i];
            acc += (float)wv2[i] * vbuf[kq * 32 + 16 + i];
            acc += (float)wv3[i] * vbuf[kq * 32 + 24 + i];
        }
        acc += __shfl_xor(acc, 1);
        acc += __shfl_xor(acc, 2);
        if (kq == 0) {
            float s = acc + ((const float*)(wsb + WS_NB))[u];
            float v = fmaxf(s, 0.0f);
            long o = (long)d * 64 + u;
            if (isb) ((bf16*)outp)[o] = (bf16)v;
            else     ((float*)outp)[o] = v;
        }
    }
}

extern "C" void kernel_launch(void* const* d_in, const int* in_sizes, int n_in,
                              void* d_out, int out_size, void* d_ws, size_t ws_size,
                              hipStream_t stream) {
    gtea_prep<<<32, 256, 0, stream>>>(
        d_in[2],                                  // e_times (dtype sniff)
        d_in[5], d_in[6], d_in[7], d_in[8],       // t2v
        d_in[9], d_in[10], d_in[11], d_in[12],    // lstm_e
        d_in[13], d_in[14], d_in[15], d_in[16],   // lstm_a
        d_in[17], d_in[18], d_in[19],             // attn_w, edge_out_W, edge_out_b
        d_in[20], d_in[21],                       // node_W, node_b
        d_ws);
    gtea_lstm<<<2 * N_DSTN, 256, 0, stream>>>(
        d_in[1], d_in[2], (const int*)d_in[3], d_ws);
    gtea_epi<<<N_DSTN, 256, 0, stream>>>(
        d_in[0], (const int*)d_in[4], d_in[2], d_ws, d_out);
}

// Round 7
// 815.851 us; speedup vs baseline: 1.7848x; 1.7848x over previous
//
#include <hip/hip_runtime.h>

typedef __bf16 bf16;
typedef __bf16 bf16x8 __attribute__((ext_vector_type(8)));
typedef float f32x4 __attribute__((ext_vector_type(4)));

#define N_DSTN 8192
#define TT 16
#define HROW 72            // shorts per h row (64 + 8 pad); 144B row keeps 16B align for b128
#define HBUF (32 * HROW)   // one parity buffer, in shorts

// ---- workspace layout (bytes) ----
#define WS_WHH  0          // bf16 [2][256][64]  pre-scaled
#define WS_WIH  65536      // bf16 [2][256][16]  pre-scaled
#define WS_BIAS 81920      // f32  [2][256]      (bih+bhh)*gs
#define WS_EW   83968      // bf16 [64][128]
#define WS_NW   100352     // bf16 [64][128]
#define WS_EB   116736     // f32  [64]
#define WS_NB   116992     // f32  [64]
#define WS_ATTN 117248     // f32  [64]
#define WS_T2W  117504     // f32  [8]
#define WS_T2B  117536     // f32  [8]
#define WS_HE   131072     // bf16 [8192*32][64]  final h_e (original edge order)  33.55 MB
#define WS_SC   33685504   // f32  [8192*32]      leaky-relu attention scores       1.05 MB

__device__ __forceinline__ f32x4 MFMA(bf16x8 a, bf16x8 b, f32x4 c) {
    return __builtin_amdgcn_mfma_f32_16x16x32_bf16(a, b, c, 0, 0, 0);
}
__device__ __forceinline__ float ldf(const void* p, long i, bool isb) {
    return isb ? (float)((const bf16*)p)[i] : ((const float*)p)[i];
}
__device__ __forceinline__ bf16x8 zero8() {
    bf16x8 z;
    #pragma unroll
    for (int i = 0; i < 8; i++) z[i] = (bf16)0.0f;
    return z;
}
// 8 consecutive elements as bf16x8; i must be a multiple of 4
__device__ __forceinline__ bf16x8 ld8v(const void* p, long i, bool isb) {
    if (isb) {
        return *reinterpret_cast<const bf16x8*>((const bf16*)p + i);
    } else {
        const float* f = (const float*)p + i;
        float4 u = *reinterpret_cast<const float4*>(f);
        float4 v = *reinterpret_cast<const float4*>(f + 4);
        bf16x8 r;
        r[0] = (bf16)u.x; r[1] = (bf16)u.y; r[2] = (bf16)u.z; r[3] = (bf16)u.w;
        r[4] = (bf16)v.x; r[5] = (bf16)v.y; r[6] = (bf16)v.z; r[7] = (bf16)v.w;
        return r;
    }
}

// ---------------- prep: convert/scale all params into workspace ----------------
extern "C" __global__ void gtea_prep(const void* __restrict__ e_times,
                                     const void* __restrict__ t2v_w,
                                     const void* __restrict__ t2v_b,
                                     const void* __restrict__ t2v_w0,
                                     const void* __restrict__ t2v_b0,
                                     const void* __restrict__ Wih_e,
                                     const void* __restrict__ Whh_e,
                                     const void* __restrict__ bih_e,
                                     const void* __restrict__ bhh_e,
                                     const void* __restrict__ Wih_a,
                                     const void* __restrict__ Whh_a,
                                     const void* __restrict__ bih_a,
                                     const void* __restrict__ bhh_a,
                                     const void* __restrict__ attn_w,
                                     const void* __restrict__ edge_out_W,
                                     const void* __restrict__ edge_out_b,
                                     const void* __restrict__ node_W,
                                     const void* __restrict__ node_b,
                                     void* __restrict__ ws)
{
    __shared__ int isb_s;
    const int tid = threadIdx.x;
    if (tid < 64) {
        const unsigned short* u = (const unsigned short*)e_times;
        unsigned short a = u[tid * 2], b = u[tid * 2 + 1];
        bool ok = (a <= 0x3F80u) && (b <= 0x3F80u);
        unsigned long long m = __ballot(ok);
        if (tid == 0) isb_s = (m == ~0ULL) ? 1 : 0;
    }
    __syncthreads();
    const bool isb = (isb_s != 0);
    char* wsb = (char*)ws;
    const int gstep = blockDim.x * gridDim.x;
    const int g0 = blockIdx.x * blockDim.x + tid;

    // Whh scaled: [2][256][64]
    for (int i = g0; i < 2 * 256 * 64; i += gstep) {
        int Lw = i >> 14, rem = i & 16383, n = rem >> 6;
        const void* W = Lw ? Whh_a : Whh_e;
        float gs = ((n >> 6) == 2) ? 2.88539008f : -1.44269504f;
        ((bf16*)(wsb + WS_WHH))[i] = (bf16)(ldf(W, rem, isb) * gs);
    }
    // Wih scaled: [2][256][16]
    for (int i = g0; i < 2 * 256 * 16; i += gstep) {
        int Lw = i >> 12, rem = i & 4095, n = rem >> 4;
        const void* W = Lw ? Wih_a : Wih_e;
        float gs = ((n >> 6) == 2) ? 2.88539008f : -1.44269504f;
        ((bf16*)(wsb + WS_WIH))[i] = (bf16)(ldf(W, rem, isb) * gs);
    }
    // bias scaled: [2][256]
    for (int i = g0; i < 2 * 256; i += gstep) {
        int Lw = i >> 8, n = i & 255;
        const void* bi = Lw ? bih_a : bih_e;
        const void* bh = Lw ? bhh_a : bhh_e;
        float gs = ((n >> 6) == 2) ? 2.88539008f : -1.44269504f;
        ((float*)(wsb + WS_BIAS))[i] = (ldf(bi, n, isb) + ldf(bh, n, isb)) * gs;
    }
    // edge_out_W / node_W → bf16
    for (int i = g0; i < 64 * 128; i += gstep) {
        ((bf16*)(wsb + WS_EW))[i] = (bf16)ldf(edge_out_W, i, isb);
        ((bf16*)(wsb + WS_NW))[i] = (bf16)ldf(node_W, i, isb);
    }
    for (int i = g0; i < 64; i += gstep) {
        ((float*)(wsb + WS_EB))[i]   = ldf(edge_out_b, i, isb);
        ((float*)(wsb + WS_NB))[i]   = ldf(node_b, i, isb);
        ((float*)(wsb + WS_ATTN))[i] = ldf(attn_w, i, isb);
    }
    if (g0 < 7) {
        ((float*)(wsb + WS_T2W))[g0] = ldf(t2v_w, g0, isb);
        ((float*)(wsb + WS_T2B))[g0] = ldf(t2v_b, g0, isb);
    }
    if (g0 == 7) {
        ((float*)(wsb + WS_T2W))[7] = ldf(t2v_w0, 0, isb);
        ((float*)(wsb + WS_T2B))[7] = ldf(t2v_b0, 0, isb);
    }
}

// ---------------- K1: LSTM kernel — one (edge-group, L) per 256-thread block ----------------
extern "C" __global__ void __launch_bounds__(256, 4)
gtea_lstm(const void* __restrict__ edge_feats,
          const void* __restrict__ e_times,
          const int*  __restrict__ e_len,
          void* __restrict__ ws)
{
    // LDS ≈ 28.1 KB; occupancy is register-tier-limited (4 waves/SIMD at 128-reg budget)
    __shared__ __align__(16) bf16 habuf[2][HBUF];        // 9216 B (parity double-buffer)
    __shared__ __align__(16) bf16 xslab[2 * 512 + 64];   // 2176 B (rolling x: feat|tenc, padded)
    __shared__ __align__(16) bf16 wihb[256 * 32];        // 16384 B ([16 w | 16 zero] per row)
    __shared__ int lens_sh[32], idx_sh[32];
    __shared__ int isb_sh;

    const int tid = threadIdx.x;
    const int w4  = tid >> 6;        // wave 0..3
    const int l   = tid & 63;
    const int l15 = l & 15;
    const int q   = l >> 4;
    const int u16 = w4 * 16 + l15;

    const int g  = blockIdx.x >> 1;
    const int L  = blockIdx.x & 1;   // 0: lstm_e, 1: lstm_a
    const int e0 = g * 32;
    char* wsb = (char*)ws;

    // ---- phase A: dtype sniff + length sort + xslab zero-fill ----
    // CORRECTNESS (R6 lesson): every xslab byte a lane can read must be written —
    // uninitialized LDS can be NaN/Inf, and NaN*0 = NaN inside the MFMA K-sum.
    {
        unsigned int* xz = reinterpret_cast<unsigned int*>(xslab);
        for (int i = tid; i < (2 * 512 + 64) / 2; i += 256) xz[i] = 0u;
    }
    if (tid < 64) {
        const unsigned short* u = (const unsigned short*)e_times;
        unsigned short a = u[tid * 2], b = u[tid * 2 + 1];
        bool ok = (a <= 0x3F80u) && (b <= 0x3F80u);
        unsigned long long m = __ballot(ok);
        if (tid == 0) isb_sh = (m == ~0ULL) ? 1 : 0;
    }
    if (tid < 32) {
        int lj = e_len[e0 + tid];
        int rank = 0;
        for (int i = 0; i < 32; i++) {
            int li = __shfl(lj, i);
            rank += (li > lj) || (li == lj && i < tid);
        }
        int mt = rank >> 4, kp = rank & 15;
        int slot = mt * 16 + (kp & 3) * 4 + (kp >> 2);
        idx_sh[slot]  = tid;
        lens_sh[slot] = lj;
    }
    __syncthreads();
    const bool isb = (isb_sh != 0);

    // ---- phase B: stage padded Wih, derive masks, load Bh/bias, prefetch x(t=0) ----
    {
        const bf16* src = (const bf16*)(wsb + WS_WIH) + L * 256 * 16 + tid * 16;
        bf16* dst = &wihb[tid * 32];
        *reinterpret_cast<bf16x8*>(dst)      = *reinterpret_cast<const bf16x8*>(src);
        *reinterpret_cast<bf16x8*>(dst + 8)  = *reinterpret_cast<const bf16x8*>(src + 8);
        *reinterpret_cast<bf16x8*>(dst + 16) = zero8();
        *reinterpret_cast<bf16x8*>(dst + 24) = zero8();
    }
    int gm0[4], gm1[4];
    #pragma unroll
    for (int r = 0; r < 4; r++) {
        gm0[r] = __builtin_amdgcn_readfirstlane(lens_sh[r]);
        gm1[r] = __builtin_amdgcn_readfirstlane(lens_sh[16 + r]);
    }
    const int tmax = gm0[0], mtmax1 = gm1[0];

    unsigned lp = 0;
    #pragma unroll
    for (int mt = 0; mt < 2; mt++)
        #pragma unroll
        for (int r = 0; r < 4; r++)
            lp |= (unsigned)(lens_sh[mt * 16 + q * 4 + r] - 1) << ((mt * 4 + r) * 4);

    const bf16*  wWhh  = (const bf16*)(wsb + WS_WHH) + (long)L * 256 * 64;
    const float* wBias = (const float*)(wsb + WS_BIAS) + L * 256;
    bf16x8 Bh[4][2];
    float  bias[4];
    #pragma unroll
    for (int j = 0; j < 4; j++) {
        int n = 64 * j + u16;
        Bh[j][0] = *reinterpret_cast<const bf16x8*>(wWhh + (long)n * 64 + q * 8);
        Bh[j][1] = *reinterpret_cast<const bf16x8*>(wWhh + (long)n * 64 + 32 + q * 8);
        bias[j] = wBias[n];
    }

    // rolling-x prefetch: 8 lanes per wave, 1 edge each (writes parity slab only)
    auto prefetch_x = [&](int t, int par) {
        int s = w4 * 8 + (l & 7);
        int j = idx_sh[s];
        long base = (long)(e0 + j) * TT + t;
        bf16x8 f8 = ld8v(edge_feats, base * 8, isb);
        float tau = ldf(e_times, base, isb);
        const float* tw = (const float*)(wsb + WS_T2W);
        const float* tb = (const float*)(wsb + WS_T2B);
        bf16x8 te;
        #pragma unroll
        for (int i = 0; i < 7; i++) te[i] = (bf16)__sinf(tau * tw[i] + tb[i]);
        te[7] = (bf16)(tau * tw[7] + tb[7]);
        *reinterpret_cast<bf16x8*>(&xslab[par * 512 + s * 16])     = f8;
        *reinterpret_cast<bf16x8*>(&xslab[par * 512 + s * 16 + 8]) = te;
    };
    if (l < 8) prefetch_x(0, 0);

    // unconditional per-lane addressing: q>=2 lanes hit the zero half of wihb rows
    // and read finite (zero-filled or stale-but-finite) xslab data — product is exactly 0.
    const bf16* bxp   = &wihb[u16 * 32 + q * 8];         // + j*2048 per gate
    const bf16* xbase = &xslab[l15 * 16 + q * 8];        // + mt*256 + par*512

    const int rd_off = l15 * HROW + q * 8;
    const int wr_off = (q * 4) * HROW + u16;

    float c[2][4];
    #pragma unroll
    for (int mt = 0; mt < 2; mt++)
        #pragma unroll
        for (int r = 0; r < 4; r++) c[mt][r] = 0.0f;

    __syncthreads();

    // shared activation (gates pre-scaled: gi,gf,go = -x/ln2 ; gg = +2x/ln2)
    auto activ = [&](f32x4 (&D)[4], int mt, int r, bf16* hw) {
        float gi = D[0][r], gf = D[1][r];
        float gg = D[2][r], go = D[3][r];
        float ei = __builtin_amdgcn_exp2f(gi);
        float ef = __builtin_amdgcn_exp2f(gf);
        float eg = __builtin_amdgcn_exp2f(gg);
        float di = 1.0f + ei, dfv = 1.0f + ef, dg = 1.0f + eg;
        float m1 = di * dg;
        float R1 = __builtin_amdgcn_rcpf(m1 * dfv);
        float cn = (m1 * R1) * c[mt][r] + (eg - 1.0f) * (dfv * R1);
        c[mt][r] = cn;
        float eo = __builtin_amdgcn_exp2f(go);
        float ec = __builtin_amdgcn_exp2f(2.88539008f * cn);
        float R2 = __builtin_amdgcn_rcpf((1.0f + eo) * (1.0f + ec));
        float hn = (ec - 1.0f) * R2;
        hw[r * HROW] = (bf16)hn;
    };

    // ---- peeled t=0: h == 0, so no h-MFMAs, unmasked (all lens >= 1) ----
    {
        bf16* wp = &habuf[1][0] + wr_off;
        #pragma unroll
        for (int mt = 0; mt < 2; mt++) {
            bf16x8 xa = *reinterpret_cast<const bf16x8*>(xbase + mt * 256);
            f32x4 D[4];
            #pragma unroll
            for (int j = 0; j < 4; j++) {
                f32x4 acc = {bias[j], bias[j], bias[j], bias[j]};
                bf16x8 bx = *reinterpret_cast<const bf16x8*>(bxp + j * 2048);
                acc = MFMA(xa, bx, acc);
                D[j] = acc;
            }
            bf16* hw = wp + mt * (16 * HROW);
            #pragma unroll
            for (int r = 0; r < 4; r++) activ(D, mt, r, hw);
        }
        if (l < 8 && 1 < tmax) prefetch_x(1, 1);
        __syncthreads();
    }

    // ---- main recurrent loop ----
    auto do_mt = [&](int mt, int t, const bf16* rp, bf16* wp, const bf16* xpt) {
        const bf16* hr = rp + mt * (16 * HROW);
        bf16x8 ah0 = *reinterpret_cast<const bf16x8*>(hr);
        bf16x8 ah1 = *reinterpret_cast<const bf16x8*>(hr + 32);
        bf16x8 xa  = *reinterpret_cast<const bf16x8*>(xpt + mt * 256);
        f32x4 D[4];
        #pragma unroll
        for (int j = 0; j < 4; j++) {
            f32x4 acc = {bias[j], bias[j], bias[j], bias[j]};
            acc = MFMA(ah0, Bh[j][0], acc);
            acc = MFMA(ah1, Bh[j][1], acc);
            bf16x8 bx = *reinterpret_cast<const bf16x8*>(bxp + j * 2048);
            acc = MFMA(xa, bx, acc);
            D[j] = acc;
        }
        bf16* hw = wp + mt * (16 * HROW);
        #pragma unroll
        for (int r = 0; r < 4; r++) {
            int gmax = mt ? gm1[r] : gm0[r];
            if (t < gmax) {
                int lm1 = (int)((lp >> ((mt * 4 + r) * 4)) & 15u);
                if (t <= lm1) activ(D, mt, r, hw);
            }
        }
    };

    for (int t = 1; t < tmax; t++) {
        const bf16* rp = &habuf[t & 1][0] + rd_off;
        bf16*       wp = &habuf[(t + 1) & 1][0] + wr_off;
        const bf16* xpt = xbase + (t & 1) * 512;
        do_mt(0, t, rp, wp, xpt);
        if (t < mtmax1) do_mt(1, t, rp, wp, xpt);
        if (l < 8 && t + 1 < tmax) prefetch_x(t + 1, (t + 1) & 1);
        __syncthreads();
    }

    // ---- finalize: write h_last (L=0) or attention scores (L=1), original edge order ----
    {
        int s = tid >> 3, c8 = tid & 7;
        const bf16* ha = &habuf[lens_sh[s] & 1][s * HROW + c8 * 8];
        bf16x8 hv = *reinterpret_cast<const bf16x8*>(ha);
        if (L == 0) {
            *reinterpret_cast<bf16x8*>((bf16*)(wsb + WS_HE) +
                ((long)(e0 + idx_sh[s])) * 64 + c8 * 8) = hv;
        } else {
            const float* af = (const float*)(wsb + WS_ATTN);
            float p = 0.0f;
            #pragma unroll
            for (int i = 0; i < 8; i++) p += (float)hv[i] * af[c8 * 8 + i];
            p += __shfl_xor(p, 1);
            p += __shfl_xor(p, 2);
            p += __shfl_xor(p, 4);
            if (c8 == 0)
                ((float*)(wsb + WS_SC))[e0 + idx_sh[s]] = (p > 0.0f) ? p : 0.01f * p;
        }
    }
}

// ---------------- K2: epilogue — sparsemax + m-GEMM + h_neigh + output ----------------
extern "C" __global__ void __launch_bounds__(256, 4)
gtea_epi(const void* __restrict__ node_features,
         const int*  __restrict__ edge_src,
         const void* __restrict__ e_times,
         const void* __restrict__ ws,
         void* __restrict__ outp)
{
    __shared__ float vbuf[128];
    __shared__ float alpha_sh[32];
    __shared__ int isb_sh;

    const int tid = threadIdx.x;
    const int w4  = tid >> 6;
    const int l   = tid & 63;
    const int l15 = l & 15;
    const int q   = l >> 4;
    const int u16 = w4 * 16 + l15;

    const int d  = blockIdx.x;
    const int e0 = d * 32;
    const char* wsb = (const char*)ws;

    if (tid < 64) {
        const unsigned short* u = (const unsigned short*)e_times;
        unsigned short a = u[tid * 2], b = u[tid * 2 + 1];
        bool ok = (a <= 0x3F80u) && (b <= 0x3F80u);
        unsigned long long m = __ballot(ok);
        if (tid == 0) isb_sh = (m == ~0ULL) ? 1 : 0;
    }
    __syncthreads();
    const bool isb = (isb_sh != 0);

    if (tid < 64) vbuf[tid] = ldf(node_features, (long)d * 64 + tid, isb);

    // m = relu([h_src | h_e] @ edge_out_W^T + b)   (original edge order)
    float mval[2][4];
    {
        const bf16* wEW = (const bf16*)(wsb + WS_EW);
        bf16x8 Bw[4];
        #pragma unroll
        for (int ks = 0; ks < 4; ks++)
            Bw[ks] = *reinterpret_cast<const bf16x8*>(wEW + (long)u16 * 128 + ks * 32 + q * 8);
        float mb = ((const float*)(wsb + WS_EB))[u16];
        const bf16* hE = (const bf16*)(wsb + WS_HE);
        #pragma unroll
        for (int mt = 0; mt < 2; mt++) {
            int e_loc = mt * 16 + l15;
            int src = edge_src[e0 + e_loc];
            bf16x8 a0 = ld8v(node_features, (long)src * 64 + q * 8, isb);
            bf16x8 a1 = ld8v(node_features, (long)src * 64 + 32 + q * 8, isb);
            bf16x8 a2 = *reinterpret_cast<const bf16x8*>(hE + (long)(e0 + e_loc) * 64 + q * 8);
            bf16x8 a3 = *reinterpret_cast<const bf16x8*>(hE + (long)(e0 + e_loc) * 64 + 32 + q * 8);
            f32x4 acc = {mb, mb, mb, mb};
            acc = MFMA(a0, Bw[0], acc);
            acc = MFMA(a1, Bw[1], acc);
            acc = MFMA(a2, Bw[2], acc);
            acc = MFMA(a3, Bw[3], acc);
            #pragma unroll
            for (int r = 0; r < 4; r++) mval[mt][r] = fmaxf(acc[r], 0.0f);
        }
    }

    if (tid < 64) {   // sparsemax (reference-exact)
        float z = (tid < 32) ? ((const float*)(wsb + WS_SC))[e0 + tid] : -3.0e38f;
        float zm = z;
        #pragma unroll
        for (int m = 32; m >= 1; m >>= 1) zm = fmaxf(zm, __shfl_xor(zm, m));
        z -= zm;
        int cnt = 0; float sb = 0.0f;
        for (int i = 0; i < 32; i++) {
            float zi = __shfl(z, i);
            bool before = (zi > z) || (zi == z && i < tid);
            if (before) { cnt++; sb += zi; }
        }
        float r = (float)(cnt + 1);
        float S = sb + z;
        bool isgt = (tid < 32) && (1.0f + r * z > S);
        float kf  = isgt ? r : 0.0f;
        float sgt = isgt ? z : 0.0f;
        #pragma unroll
        for (int m = 32; m >= 1; m >>= 1) kf = fmaxf(kf, __shfl_xor(kf, m));
        #pragma unroll
        for (int m = 32; m >= 1; m >>= 1) sgt += __shfl_xor(sgt, m);
        float tau = (sgt - 1.0f) / fmaxf(kf, 1.0f);
        if (tid < 32) alpha_sh[tid] = fmaxf(z - tau, 0.0f);
    }
    __syncthreads();

    {   // h_neigh
        float hn = 0.0f;
        #pragma unroll
        for (int mt = 0; mt < 2; mt++)
            #pragma unroll
            for (int r = 0; r < 4; r++)
                hn += alpha_sh[mt * 16 + q * 4 + r] * mval[mt][r];
        hn += __shfl_xor(hn, 16);
        hn += __shfl_xor(hn, 32);
        if (q == 0) vbuf[64 + u16] = hn;
    }
    __syncthreads();

    {   // final matvec, in-wave 4-way reduction
        int u = tid >> 2, kq = tid & 3;
        const bf16* wNW = (const bf16*)(wsb + WS_NW);
        bf16x8 wv0 = *reinterpret_cast<const bf16x8*>(wNW + (long)u * 128 + kq * 32);
        bf16x8 wv1 = *reinterpret_cast<const bf16x8*>(wNW + (long)u * 128 + kq * 32 + 8);
        bf16x8 wv2 = *reinterpret_cast<const bf16x8*>(wNW + (long)u * 128 + kq * 32 + 16);
        bf16x8 wv3 = *reinterpret_cast<const bf16x8*>(wNW + (long)u * 128 + kq * 32 + 24);
        float acc = 0.0f;
        #pragma unroll
        for (int i = 0; i < 8; i++) {
            acc += (float)wv0[i] * vbuf[kq * 32 + i];
            acc += (float)wv1[i] * vbuf[kq * 32 + 8 + i];
            acc += (float)wv2[i] * vbuf[kq * 32 + 16 + i];
            acc += (float)wv3[i] * vbuf[kq * 32 + 24 + i];
        }
        acc += __shfl_xor(acc, 1);
        acc += __shfl_xor(acc, 2);
        if (kq == 0) {
            float s = acc + ((const float*)(wsb + WS_NB))[u];
            float v = fmaxf(s, 0.0f);
            long o = (long)d * 64 + u;
            if (isb) ((bf16*)outp)[o] = (bf16)v;
            else     ((float*)outp)[o] = v;
        }
    }
}

extern "C" void kernel_launch(void* const* d_in, const int* in_sizes, int n_in,
                              void* d_out, int out_size, void* d_ws, size_t ws_size,
                              hipStream_t stream) {
    gtea_prep<<<32, 256, 0, stream>>>(
        d_in[2],                                  // e_times (dtype sniff)
        d_in[5], d_in[6], d_in[7], d_in[8],       // t2v
        d_in[9], d_in[10], d_in[11], d_in[12],    // lstm_e
        d_in[13], d_in[14], d_in[15], d_in[16],   // lstm_a
        d_in[17], d_in[18], d_in[19],             // attn_w, edge_out_W, edge_out_b
        d_in[20], d_in[21],                       // node_W, node_b
        d_ws);
    gtea_lstm<<<2 * N_DSTN, 256, 0, stream>>>(
        d_in[1], d_in[2], (const int*)d_in[3], d_ws);
    gtea_epi<<<N_DSTN, 256, 0, stream>>>(
        d_in[0], (const int*)d_in[4], d_in[2], d_ws, d_out);
}

// Round 8
// 700.660 us; speedup vs baseline: 2.0782x; 1.1644x over previous
//
#include <hip/hip_runtime.h>

typedef __bf16 bf16;
typedef __bf16 bf16x8 __attribute__((ext_vector_type(8)));
typedef float f32x4 __attribute__((ext_vector_type(4)));

#define N_DSTN 8192
#define TT 16
#define HROW 72            // shorts per h row (64 + 8 pad); 144B row keeps 16B align for b128
#define HBUF (32 * HROW)   // one parity buffer, in shorts

// ---- workspace layout (bytes) ----
#define WS_WHH  0          // bf16 [2][256][64]  pre-scaled
#define WS_WIH  65536      // bf16 [2][256][16]  pre-scaled
#define WS_BIAS 81920      // f32  [2][256]      (bih+bhh)*gs
#define WS_EW   83968      // bf16 [64][128]
#define WS_NW   100352     // bf16 [64][128]
#define WS_EB   116736     // f32  [64]
#define WS_NB   116992     // f32  [64]
#define WS_ATTN 117248     // f32  [64]
#define WS_T2W  117504     // f32  [8]
#define WS_T2B  117536     // f32  [8]

__device__ __forceinline__ f32x4 MFMA(bf16x8 a, bf16x8 b, f32x4 c) {
    return __builtin_amdgcn_mfma_f32_16x16x32_bf16(a, b, c, 0, 0, 0);
}
__device__ __forceinline__ float ldf(const void* p, long i, bool isb) {
    return isb ? (float)((const bf16*)p)[i] : ((const float*)p)[i];
}
__device__ __forceinline__ bf16x8 zero8() {
    bf16x8 z;
    #pragma unroll
    for (int i = 0; i < 8; i++) z[i] = (bf16)0.0f;
    return z;
}
// 8 consecutive elements as bf16x8; i must be a multiple of 4
__device__ __forceinline__ bf16x8 ld8v(const void* p, long i, bool isb) {
    if (isb) {
        return *reinterpret_cast<const bf16x8*>((const bf16*)p + i);
    } else {
        const float* f = (const float*)p + i;
        float4 u = *reinterpret_cast<const float4*>(f);
        float4 v = *reinterpret_cast<const float4*>(f + 4);
        bf16x8 r;
        r[0] = (bf16)u.x; r[1] = (bf16)u.y; r[2] = (bf16)u.z; r[3] = (bf16)u.w;
        r[4] = (bf16)v.x; r[5] = (bf16)v.y; r[6] = (bf16)v.z; r[7] = (bf16)v.w;
        return r;
    }
}

// ---------------- prep: convert/scale all params into workspace ----------------
extern "C" __global__ void gtea_prep(const void* __restrict__ e_times,
                                     const void* __restrict__ t2v_w,
                                     const void* __restrict__ t2v_b,
                                     const void* __restrict__ t2v_w0,
                                     const void* __restrict__ t2v_b0,
                                     const void* __restrict__ Wih_e,
                                     const void* __restrict__ Whh_e,
                                     const void* __restrict__ bih_e,
                                     const void* __restrict__ bhh_e,
                                     const void* __restrict__ Wih_a,
                                     const void* __restrict__ Whh_a,
                                     const void* __restrict__ bih_a,
                                     const void* __restrict__ bhh_a,
                                     const void* __restrict__ attn_w,
                                     const void* __restrict__ edge_out_W,
                                     const void* __restrict__ edge_out_b,
                                     const void* __restrict__ node_W,
                                     const void* __restrict__ node_b,
                                     void* __restrict__ ws)
{
    __shared__ int isb_s;
    const int tid = threadIdx.x;
    if (tid < 64) {
        const unsigned short* u = (const unsigned short*)e_times;
        unsigned short a = u[tid * 2], b = u[tid * 2 + 1];
        bool ok = (a <= 0x3F80u) && (b <= 0x3F80u);
        unsigned long long m = __ballot(ok);
        if (tid == 0) isb_s = (m == ~0ULL) ? 1 : 0;
    }
    __syncthreads();
    const bool isb = (isb_s != 0);
    char* wsb = (char*)ws;
    const int gstep = blockDim.x * gridDim.x;
    const int g0 = blockIdx.x * blockDim.x + tid;

    // Whh scaled: [2][256][64]
    for (int i = g0; i < 2 * 256 * 64; i += gstep) {
        int Lw = i >> 14, rem = i & 16383, n = rem >> 6;
        const void* W = Lw ? Whh_a : Whh_e;
        float gs = ((n >> 6) == 2) ? 2.88539008f : -1.44269504f;
        ((bf16*)(wsb + WS_WHH))[i] = (bf16)(ldf(W, rem, isb) * gs);
    }
    // Wih scaled: [2][256][16]
    for (int i = g0; i < 2 * 256 * 16; i += gstep) {
        int Lw = i >> 12, rem = i & 4095, n = rem >> 4;
        const void* W = Lw ? Wih_a : Wih_e;
        float gs = ((n >> 6) == 2) ? 2.88539008f : -1.44269504f;
        ((bf16*)(wsb + WS_WIH))[i] = (bf16)(ldf(W, rem, isb) * gs);
    }
    // bias scaled: [2][256]
    for (int i = g0; i < 2 * 256; i += gstep) {
        int Lw = i >> 8, n = i & 255;
        const void* bi = Lw ? bih_a : bih_e;
        const void* bh = Lw ? bhh_a : bhh_e;
        float gs = ((n >> 6) == 2) ? 2.88539008f : -1.44269504f;
        ((float*)(wsb + WS_BIAS))[i] = (ldf(bi, n, isb) + ldf(bh, n, isb)) * gs;
    }
    // edge_out_W / node_W → bf16
    for (int i = g0; i < 64 * 128; i += gstep) {
        ((bf16*)(wsb + WS_EW))[i] = (bf16)ldf(edge_out_W, i, isb);
        ((bf16*)(wsb + WS_NW))[i] = (bf16)ldf(node_W, i, isb);
    }
    for (int i = g0; i < 64; i += gstep) {
        ((float*)(wsb + WS_EB))[i]   = ldf(edge_out_b, i, isb);
        ((float*)(wsb + WS_NB))[i]   = ldf(node_b, i, isb);
        ((float*)(wsb + WS_ATTN))[i] = ldf(attn_w, i, isb);
    }
    if (g0 < 7) {
        ((float*)(wsb + WS_T2W))[g0] = ldf(t2v_w, g0, isb);
        ((float*)(wsb + WS_T2B))[g0] = ldf(t2v_b, g0, isb);
    }
    if (g0 == 7) {
        ((float*)(wsb + WS_T2W))[7] = ldf(t2v_w0, 0, isb);
        ((float*)(wsb + WS_T2B))[7] = ldf(t2v_b0, 0, isb);
    }
}

// ---------------- main fused kernel (round-2 structure + peeled t=0) ----------------
extern "C" __global__ void __launch_bounds__(512, 4)
gtea_fused(const void* __restrict__ node_features,
           const void* __restrict__ edge_feats,
           const void* __restrict__ e_times,
           const int*  __restrict__ e_len,
           const int*  __restrict__ edge_src,
           const void* __restrict__ ws,
           void* __restrict__ outp)
{
    __shared__ __align__(16) bf16 habuf[2][2][HBUF];   // [L][parity]  18432 B
    __shared__ __align__(16) bf16 featb[TT * 32 * 8];  // 8192 B
    __shared__ __align__(16) bf16 tb[TT * 32 * 8];     // 8192 B
    __shared__ float t2w[8], t2b[8];
    __shared__ float attn_f[64];
    __shared__ float vbuf[128];
    __shared__ float scores_sh[32], alpha_sh[32];
    __shared__ int   lens_sh[32], idx_sh[32];
    __shared__ int   isb_sh;

    const int tid = threadIdx.x;
    const int w   = tid >> 6;
    const int l   = tid & 63;
    const int l15 = l & 15;
    const int q   = l >> 4;
    const int L   = w >> 2;          // 0: lstm_e, 1: lstm_a
    const int w4  = w & 3;
    const int u16 = w4 * 16 + l15;

    const int d  = blockIdx.x;
    const int e0 = d * 32;
    const char* wsb = (const char*)ws;

    // ---- dtype sniff ----
    if (tid < 64) {
        const unsigned short* u = (const unsigned short*)e_times;
        unsigned short a = u[tid * 2], b = u[tid * 2 + 1];
        bool ok = (a <= 0x3F80u) && (b <= 0x3F80u);
        unsigned long long m = __ballot(ok);
        if (tid == 0) isb_sh = (m == ~0ULL) ? 1 : 0;
    }
    // ---- in-wave length sort (wave 0) ----
    if (tid < 32) {
        int lj = e_len[e0 + tid];
        int rank = 0;
        for (int i = 0; i < 32; i++) {
            int li = __shfl(lj, i);
            rank += (li > lj) || (li == lj && i < tid);
        }
        int mt = rank >> 4, kp = rank & 15;
        int slot = mt * 16 + (kp & 3) * 4 + (kp >> 2);
        idx_sh[slot]  = tid;
        lens_sh[slot] = lj;
    }
    __syncthreads();
    const bool isb = (isb_sh != 0);

    // ---- S0: params from ws, h_dst ----
    // NOTE: habuf is NOT zero-initialized. t=0 is peeled (h==0 exactly, no h-MFMAs).
    // Stale/uninitialized habuf rows are only ever multiplied into the MFMA A-rows of
    // DEAD edges (t >= len), whose D columns are masked at activ and never read at
    // finalize (finalize reads parity len&1, written at t=len-1). R7 validated this.
    if (tid < 8)  { t2w[tid] = ((const float*)(wsb + WS_T2W))[tid];
                    t2b[tid] = ((const float*)(wsb + WS_T2B))[tid]; }
    if (tid < 64) attn_f[tid] = ((const float*)(wsb + WS_ATTN))[tid];
    if (tid < 64) vbuf[tid] = ldf(node_features, (long)d * 64 + tid, isb);
    __syncthreads();

    // ---- S2: edge staging + weights from ws ----
    int gm0[4], gm1[4];
    #pragma unroll
    for (int r = 0; r < 4; r++) {
        gm0[r] = __builtin_amdgcn_readfirstlane(lens_sh[r]);
        gm1[r] = __builtin_amdgcn_readfirstlane(lens_sh[16 + r]);
    }
    const int tmax = gm0[0], mtmax1 = gm1[0];

    unsigned lp = 0;
    #pragma unroll
    for (int mt = 0; mt < 2; mt++)
        #pragma unroll
        for (int r = 0; r < 4; r++)
            lp |= (unsigned)(lens_sh[mt * 16 + q * 4 + r] - 1) << ((mt * 4 + r) * 4);

    {
        int s = tid >> 4, t = tid & 15;
        int j = idx_sh[s];
        long base = ((long)(e0 + j) * TT + t) * 8;
        *reinterpret_cast<bf16x8*>(&featb[(t * 32 + s) * 8]) = ld8v(edge_feats, base, isb);
        float tau = ldf(e_times, (long)(e0 + j) * TT + t, isb);
        bf16x8 te;
        #pragma unroll
        for (int i = 0; i < 7; i++) te[i] = (bf16)__sinf(tau * t2w[i] + t2b[i]);
        te[7] = (bf16)(tau * t2w[7] + t2b[7]);
        *reinterpret_cast<bf16x8*>(&tb[(t * 32 + s) * 8]) = te;
    }

    const bf16*  wWhh  = (const bf16*)(wsb + WS_WHH) + (long)L * 256 * 64;
    const bf16*  wWih  = (const bf16*)(wsb + WS_WIH) + (long)L * 256 * 16;
    const float* wBias = (const float*)(wsb + WS_BIAS) + L * 256;
    bf16x8 Bh[4][2], Bx[4];
    float  bias[4];
    #pragma unroll
    for (int j = 0; j < 4; j++) {
        int n = 64 * j + u16;
        Bh[j][0] = *reinterpret_cast<const bf16x8*>(wWhh + (long)n * 64 + q * 8);
        Bh[j][1] = *reinterpret_cast<const bf16x8*>(wWhh + (long)n * 64 + 32 + q * 8);
        Bx[j] = (q < 2) ? *reinterpret_cast<const bf16x8*>(wWih + (long)n * 16 + q * 8) : zero8();
        bias[j] = wBias[n];
    }

    float c[2][4];
    #pragma unroll
    for (int mt = 0; mt < 2; mt++)
        #pragma unroll
        for (int r = 0; r < 4; r++) c[mt][r] = 0.0f;

    __syncthreads();

    // shared activation (gates pre-scaled: gi,gf,go = -x/ln2 ; gg = +2x/ln2)
    auto activ = [&](f32x4 (&D)[4], int mt, int r, bf16* hw) {
        float gi = D[0][r], gf = D[1][r];
        float gg = D[2][r], go = D[3][r];
        float ei = __builtin_amdgcn_exp2f(gi);
        float ef = __builtin_amdgcn_exp2f(gf);
        float eg = __builtin_amdgcn_exp2f(gg);
        float di = 1.0f + ei, dfv = 1.0f + ef, dg = 1.0f + eg;
        float m1 = di * dg;
        float R1 = __builtin_amdgcn_rcpf(m1 * dfv);
        float cn = (m1 * R1) * c[mt][r] + (eg - 1.0f) * (dfv * R1);
        c[mt][r] = cn;
        float eo = __builtin_amdgcn_exp2f(go);
        float ec = __builtin_amdgcn_exp2f(2.88539008f * cn);
        float R2 = __builtin_amdgcn_rcpf((1.0f + eo) * (1.0f + ec));
        float hn = (ec - 1.0f) * R2;
        hw[r * HROW] = (bf16)hn;
    };

    // ---- recurrent loop: double-buffered h, 1 barrier/step ----
    bf16* hb_base = &habuf[L][0][0];
    const int rd_off = l15 * HROW + q * 8;
    const int wr_off = (q * 4) * HROW + u16;

    // ---- peeled t=0: h == 0 → x-MFMA only, unmasked (all lens >= 1), write parity 1 ----
    {
        bf16* wp = hb_base + HBUF + wr_off;
        #pragma unroll
        for (int mt = 0; mt < 2; mt++) {
            bf16x8 xa;
            if (q < 2) {
                const bf16* xp = (q == 0 ? featb : tb) + (mt * 16 + l15) * 8;
                xa = *reinterpret_cast<const bf16x8*>(xp);
            } else {
                xa = zero8();
            }
            f32x4 D[4];
            #pragma unroll
            for (int j = 0; j < 4; j++) {
                f32x4 acc = {bias[j], bias[j], bias[j], bias[j]};
                acc = MFMA(xa, Bx[j], acc);
                D[j] = acc;
            }
            bf16* hw = wp + mt * (16 * HROW);
            #pragma unroll
            for (int r = 0; r < 4; r++) activ(D, mt, r, hw);
        }
        __syncthreads();
    }

    for (int t = 1; t < tmax; t++) {
        const bf16* hbR = hb_base + (t & 1) * HBUF;
        bf16*       hbW = hb_base + ((t + 1) & 1) * HBUF;

        auto do_mt = [&](int mt) {
            const bf16* hr = hbR + mt * (16 * HROW) + rd_off;
            bf16x8 ah0 = *reinterpret_cast<const bf16x8*>(hr);
            bf16x8 ah1 = *reinterpret_cast<const bf16x8*>(hr + 32);
            bf16x8 xa;
            if (q < 2) {
                const bf16* xp = (q == 0 ? featb : tb) + (t * 32 + mt * 16 + l15) * 8;
                xa = *reinterpret_cast<const bf16x8*>(xp);
            } else {
                xa = zero8();
            }
            f32x4 D[4];
            #pragma unroll
            for (int j = 0; j < 4; j++) {
                f32x4 acc = {bias[j], bias[j], bias[j], bias[j]};
                acc = MFMA(ah0, Bh[j][0], acc);
                acc = MFMA(ah1, Bh[j][1], acc);
                acc = MFMA(xa,  Bx[j],    acc);
                D[j] = acc;
            }
            bf16* hw = hbW + mt * (16 * HROW) + wr_off;
            #pragma unroll
            for (int r = 0; r < 4; r++) {
                int gmax = mt ? gm1[r] : gm0[r];
                if (t < gmax) {
                    int lm1 = (int)((lp >> ((mt * 4 + r) * 4)) & 15u);
                    if (t <= lm1) activ(D, mt, r, hw);
                }
            }
        };
        do_mt(0);
        if (t < mtmax1) do_mt(1);
        __syncthreads();
    }

    // ---- epilogue ----
    if (tid < 256) {   // attention scores
        int s = tid >> 3, c8 = tid & 7;
        const bf16* ha = &habuf[1][lens_sh[s] & 1][s * HROW];
        float p = 0.0f;
        #pragma unroll
        for (int i = 0; i < 8; i++)
            p += (float)ha[c8 * 8 + i] * attn_f[c8 * 8 + i];
        p += __shfl_xor(p, 1);
        p += __shfl_xor(p, 2);
        p += __shfl_xor(p, 4);
        if (c8 == 0) scores_sh[s] = (p > 0.0f) ? p : 0.01f * p;
    }
    float mval[2][4];
    if (tid < 256) {   // m = relu([h_src | h_e] @ edge_out_W^T + b)
        const bf16* wEW = (const bf16*)(wsb + WS_EW);
        bf16x8 Bw[4];
        #pragma unroll
        for (int ks = 0; ks < 4; ks++)
            Bw[ks] = *reinterpret_cast<const bf16x8*>(wEW + (long)u16 * 128 + ks * 32 + q * 8);
        float mb = ((const float*)(wsb + WS_EB))[u16];
        #pragma unroll
        for (int mt = 0; mt < 2; mt++) {
            int s = mt * 16 + l15;
            int src = edge_src[e0 + idx_sh[s]];
            bf16x8 a0 = ld8v(node_features, (long)src * 64 + q * 8, isb);
            bf16x8 a1 = ld8v(node_features, (long)src * 64 + 32 + q * 8, isb);
            const bf16* he = &habuf[0][lens_sh[s] & 1][s * HROW];
            bf16x8 a2 = *reinterpret_cast<const bf16x8*>(he + q * 8);
            bf16x8 a3 = *reinterpret_cast<const bf16x8*>(he + 32 + q * 8);
            f32x4 acc = {mb, mb, mb, mb};
            acc = MFMA(a0, Bw[0], acc);
            acc = MFMA(a1, Bw[1], acc);
            acc = MFMA(a2, Bw[2], acc);
            acc = MFMA(a3, Bw[3], acc);
            #pragma unroll
            for (int r = 0; r < 4; r++) mval[mt][r] = fmaxf(acc[r], 0.0f);
        }
    }
    __syncthreads();

    if (tid < 64) {   // sparsemax (reference-exact)
        float z = (tid < 32) ? scores_sh[tid] : -3.0e38f;
        float zm = z;
        #pragma unroll
        for (int m = 32; m >= 1; m >>= 1) zm = fmaxf(zm, __shfl_xor(zm, m));
        z -= zm;
        int cnt = 0; float sb = 0.0f;
        for (int i = 0; i < 32; i++) {
            float zi = __shfl(z, i);
            bool before = (zi > z) || (zi == z && i < tid);
            if (before) { cnt++; sb += zi; }
        }
        float r = (float)(cnt + 1);
        float S = sb + z;
        bool isgt = (tid < 32) && (1.0f + r * z > S);
        float kf  = isgt ? r : 0.0f;
        float sgt = isgt ? z : 0.0f;
        #pragma unroll
        for (int m = 32; m >= 1; m >>= 1) kf = fmaxf(kf, __shfl_xor(kf, m));
        #pragma unroll
        for (int m = 32; m >= 1; m >>= 1) sgt += __shfl_xor(sgt, m);
        float tau = (sgt - 1.0f) / fmaxf(kf, 1.0f);
        if (tid < 32) alpha_sh[tid] = fmaxf(z - tau, 0.0f);
    }
    __syncthreads();

    if (tid < 256) {   // h_neigh
        float hn = 0.0f;
        #pragma unroll
        for (int mt = 0; mt < 2; mt++)
            #pragma unroll
            for (int r = 0; r < 4; r++)
                hn += alpha_sh[mt * 16 + q * 4 + r] * mval[mt][r];
        hn += __shfl_xor(hn, 16);
        hn += __shfl_xor(hn, 32);
        if (q == 0) vbuf[64 + u16] = hn;
    }
    __syncthreads();

    if (tid < 256) {   // final matvec, in-wave 4-way reduction
        int u = tid >> 2, kq = tid & 3;
        const bf16* wNW = (const bf16*)(wsb + WS_NW);
        bf16x8 wv0 = *reinterpret_cast<const bf16x8*>(wNW + (long)u * 128 + kq * 32);
        bf16x8 wv1 = *reinterpret_cast<const bf16x8*>(wNW + (long)u * 128 + kq * 32 + 8);
        bf16x8 wv2 = *reinterpret_cast<const bf16x8*>(wNW + (long)u * 128 + kq * 32 + 16);
        bf16x8 wv3 = *reinterpret_cast<const bf16x8*>(wNW + (long)u * 128 + kq * 32 + 24);
        float acc = 0.0f;
        #pragma unroll
        for (int i = 0; i < 8; i++) {
            acc += (float)wv0[i] * vbuf[kq * 32 + i];
            acc += (float)wv1[i] * vbuf[kq * 32 + 8 + i];
            acc += (float)wv2[i] * vbuf[kq * 32 + 16 + i];
            acc += (float)wv3[i] * vbuf[kq * 32 + 24 + i];
        }
        acc += __shfl_xor(acc, 1);
        acc += __shfl_xor(acc, 2);
        if (kq == 0) {
            float s = acc + ((const float*)(wsb + WS_NB))[u];
            float v = fmaxf(s, 0.0f);
            long o = (long)d * 64 + u;
            if (isb) ((bf16*)outp)[o] = (bf16)v;
            else     ((float*)outp)[o] = v;
        }
    }
}

extern "C" void kernel_launch(void* const* d_in, const int* in_sizes, int n_in,
                              void* d_out, int out_size, void* d_ws, size_t ws_size,
                              hipStream_t stream) {
    gtea_prep<<<32, 256, 0, stream>>>(
        d_in[2],                                  // e_times (dtype sniff)
        d_in[5], d_in[6], d_in[7], d_in[8],       // t2v
        d_in[9], d_in[10], d_in[11], d_in[12],    // lstm_e
        d_in[13], d_in[14], d_in[15], d_in[16],   // lstm_a
        d_in[17], d_in[18], d_in[19],             // attn_w, edge_out_W, edge_out_b
        d_in[20], d_in[21],                       // node_W, node_b
        d_ws);
    gtea_fused<<<N_DSTN, 512, 0, stream>>>(
        d_in[0], d_in[1], d_in[2],
        (const int*)d_in[3], (const int*)d_in[4],
        d_ws, d_out);
}